// Round 6
// baseline (674.205 us; speedup 1.0000x reference)
//
#include <hip/hip_runtime.h>
#include <hip/hip_bf16.h>
#include <math.h>

typedef __attribute__((ext_vector_type(8))) short short8;
typedef __attribute__((ext_vector_type(4))) float f32x4;

#define MFMA_BF16 __builtin_amdgcn_mfma_f32_16x16x32_bf16

__device__ __forceinline__ ushort f2bf(float f) {
  union { __hip_bfloat16 h; ushort u; } c;
  c.h = __float2bfloat16(f);
  return c.u;
}
// round-half-up bf16 pack (positive normal floats): cheap
__device__ __forceinline__ uint pack_bf16_ru(float a, float b) {
  uint ua = __builtin_bit_cast(uint, a) + 0x8000u;
  uint ub = __builtin_bit_cast(uint, b) + 0x8000u;
  return (ua >> 16) | (ub & 0xffff0000u);
}
__device__ __forceinline__ void async_cp16(const ushort* g, ushort* l) {
  __builtin_amdgcn_global_load_lds(
      (const __attribute__((address_space(1))) void*)g,
      (__attribute__((address_space(3))) void*)l, 16, 0, 0);
}

// ------------- fused weight fp32->bf16 conversion + bias concat (one launch) -------------
__global__ __launch_bounds__(256) void conv_all(
    const float* __restrict__ Wq, const float* __restrict__ Wk,
    const float* __restrict__ Wv, const float* __restrict__ Wo,
    const float* __restrict__ W1, const float* __restrict__ W2,
    const float* __restrict__ bq, const float* __restrict__ bk,
    const float* __restrict__ bv,
    ushort* __restrict__ wqkv, ushort* __restrict__ wo,
    ushort* __restrict__ w1, ushort* __restrict__ w2,
    float* __restrict__ bqkv) {
  int i = blockIdx.x * 256 + threadIdx.x;   // float4 index
  if (i < 3145728) {
    const float* src; ushort* dst; int off;
    if (i < 786432)        { // Wq|Wk|Wv -> concatenated wqkv [3072,1024]
      dst = wqkv; off = i;
      if (i < 262144)      src = Wq + (size_t)i * 4;
      else if (i < 524288) src = Wk + (size_t)(i - 262144) * 4;
      else                 src = Wv + (size_t)(i - 524288) * 4;
    } else if (i < 1048576) { dst = wo; off = i - 786432;  src = Wo + (size_t)off * 4; }
    else if (i < 2097152)   { dst = w1; off = i - 1048576; src = W1 + (size_t)off * 4; }
    else                    { dst = w2; off = i - 2097152; src = W2 + (size_t)off * 4; }
    float4 v = *(const float4*)src;
    ushort4 o;
    o.x = f2bf(v.x); o.y = f2bf(v.y); o.z = f2bf(v.z); o.w = f2bf(v.w);
    ((ushort4*)dst)[off] = o;
  } else if (i < 3146496) {  // biases: 3 x 256 float4
    int off = i - 3145728;
    const float* src;
    if (off < 256)      src = bq + (size_t)off * 4;
    else if (off < 512) src = bk + (size_t)(off - 256) * 4;
    else                src = bv + (size_t)(off - 512) * 4;
    ((float4*)bqkv)[off] = *(const float4*)src;
  }
}

// ---------------- layernorm: one block per 1024-float row -> bf16 ----------------
__global__ __launch_bounds__(256) void ln_kernel(const float* __restrict__ x,
    const float* __restrict__ g, const float* __restrict__ b,
    ushort* __restrict__ out) {
  const int row = blockIdx.x, t = threadIdx.x;
  float4 v = ((const float4*)(x + (size_t)row * 1024))[t];
  float s  = v.x + v.y + v.z + v.w;
  float ss = v.x*v.x + v.y*v.y + v.z*v.z + v.w*v.w;
  #pragma unroll
  for (int off = 32; off >= 1; off >>= 1) {
    s  += __shfl_xor(s, off);
    ss += __shfl_xor(ss, off);
  }
  __shared__ float red[8];
  int wv = t >> 6, ln = t & 63;
  if (ln == 0) { red[wv] = s; red[4 + wv] = ss; }
  __syncthreads();
  float S  = red[0] + red[1] + red[2] + red[3];
  float SS = red[4] + red[5] + red[6] + red[7];
  float mu  = S * (1.0f/1024.0f);
  float var = SS * (1.0f/1024.0f) - mu*mu;
  float rs  = rsqrtf(var + 1e-6f);
  float4 gv = ((const float4*)g)[t];
  float4 bv = ((const float4*)b)[t];
  ushort4 o;
  o.x = f2bf((v.x-mu)*rs*gv.x + bv.x);
  o.y = f2bf((v.y-mu)*rs*gv.y + bv.y);
  o.z = f2bf((v.z-mu)*rs*gv.z + bv.z);
  o.w = f2bf((v.w-mu)*rs*gv.w + bv.w);
  ((ushort4*)(out + (size_t)row*1024))[t] = o;
}

// ---------------- 128x128 tiled bf16 GEMM, BK=64: C[m,n] = sum_k A[m,k]*Bw[n,k] ----------
enum { EPI_QK = 0, EPI_VT = 1, EPI_WO = 2, EPI_GELU = 3, EPI_OUT = 4 };

template <int EPI>
__global__ __launch_bounds__(256) void gemm_kernel(const ushort* __restrict__ A,
    const ushort* __restrict__ Bw, const float* __restrict__ bias,
    const float* __restrict__ res, void* __restrict__ outp,
    void* __restrict__ outp2, int K, int N, float scale) {
  __shared__ ushort As[2][128 * 32];
  __shared__ ushort Bs[2][128 * 32];
  const int t = threadIdx.x;
  const int m0 = blockIdx.x * 128, n0 = blockIdx.y * 128;
  const int lane = t & 63, wave = t >> 6;
  const int col = lane & 15, quad = lane >> 4;
  const int wrow = (wave >> 1) * 64, wcol = (wave & 1) * 64;

  f32x4 acc[4][4];
  #pragma unroll
  for (int i = 0; i < 4; i++)
    #pragma unroll
    for (int j = 0; j < 4; j++)
      acc[i][j] = (f32x4){0.f, 0.f, 0.f, 0.f};

  const int lrow = lane >> 2, lcol = (lane & 3) * 8;
  const ushort* Ag = A  + (size_t)(m0 + wave * 32 + lrow) * K + lcol;
  const ushort* Bg = Bw + (size_t)(n0 + wave * 32 + lrow) * K + lcol;
  const int ldso = (wave * 32) * 32;

  for (int k0 = 0; k0 < K; k0 += 64) {
    __syncthreads();
    #pragma unroll
    for (int c = 0; c < 2; c++) {
      async_cp16(Ag + k0 + c * 32,                  &As[c][ldso]);
      async_cp16(Ag + (size_t)16 * K + k0 + c * 32, &As[c][ldso + 16 * 32]);
      async_cp16(Bg + k0 + c * 32,                  &Bs[c][ldso]);
      async_cp16(Bg + (size_t)16 * K + k0 + c * 32, &Bs[c][ldso + 16 * 32]);
    }
    __syncthreads();
    #pragma unroll
    for (int c = 0; c < 2; c++) {
      short8 af[4], bf[4];
      #pragma unroll
      for (int tm = 0; tm < 4; tm++)
        af[tm] = *(const short8*)&As[c][(wrow + tm * 16 + col) * 32 + quad * 8];
      #pragma unroll
      for (int tn = 0; tn < 4; tn++)
        bf[tn] = *(const short8*)&Bs[c][(wcol + tn * 16 + col) * 32 + quad * 8];
      #pragma unroll
      for (int tm = 0; tm < 4; tm++)
        #pragma unroll
        for (int tn = 0; tn < 4; tn++)
          acc[tm][tn] = MFMA_BF16(af[tm], bf[tn], acc[tm][tn], 0, 0, 0);
    }
  }

  #pragma unroll
  for (int tm = 0; tm < 4; tm++) {
    #pragma unroll
    for (int tn = 0; tn < 4; tn++) {
      const int n = n0 + wcol + tn * 16 + col;
      const float bn = (EPI == EPI_VT) ? 0.f : bias[n];
      #pragma unroll
      for (int r = 0; r < 4; r++) {
        const int m = m0 + wrow + tm * 16 + quad * 4 + r;
        float v = acc[tm][tn][r] + bn;
        if (EPI == EPI_QK) {
          // n in [0,2048): 0..1023 -> Q (scaled), else K
          int nl = n & 1023, h = nl >> 6, hd = nl & 63;
          int bb = m >> 11, s2 = m & 2047;
          if (n < 1024)
            ((ushort*)outp)[(((size_t)(bb * 16 + h) * 2048 + s2) * 64) + hd] = f2bf(v * scale);
          else
            ((ushort*)outp2)[(((size_t)(bb * 16 + h) * 2048 + s2) * 64) + hd] = f2bf(v);
        } else if (EPI == EPI_VT) {
          // A=Wv, Bw=xn: m = v-dim, n = token. bias indexed by m.
          float vv = v + bias[m];
          int h = m >> 6, hd = m & 63, bb = n >> 11, s2 = n & 2047;
          ((ushort*)outp)[((size_t)((bb * 16 + h) * 64 + hd)) * 2048 + s2] = f2bf(vv);
        } else if (EPI == EPI_GELU) {
          float u = v * 0.7978845608028654f * (1.0f + 0.044715f * v * v);
          float e = __builtin_amdgcn_exp2f(u * 2.885390081777927f);  // e^{2u}
          float th = 1.0f - 2.0f * __builtin_amdgcn_rcpf(e + 1.0f);
          ((ushort*)outp)[(size_t)m * N + n] = f2bf(0.5f * v * (1.0f + th));
        } else {  // EPI_WO / EPI_OUT (unused in this template now)
          ((float*)outp)[(size_t)m * N + n] = v + res[(size_t)m * N + n];
        }
      }
    }
  }
}

// ---------------- 128x64 tiled bf16 GEMM (for N=1024: 1024 blocks = 4/CU) ----------------
template <int EPI>
__global__ __launch_bounds__(256) void gemm64_kernel(const ushort* __restrict__ A,
    const ushort* __restrict__ Bw, const float* __restrict__ bias,
    const float* __restrict__ res, void* __restrict__ outp, int K, int N) {
  __shared__ ushort As[2][128 * 32];   // 16 KB
  __shared__ ushort Bs[2][64 * 32];    // 8 KB
  const int t = threadIdx.x;
  const int m0 = blockIdx.x * 128, n0 = blockIdx.y * 64;
  const int lane = t & 63, wave = t >> 6;
  const int col = lane & 15, quad = lane >> 4;
  const int wrow = (wave >> 1) * 64, wcol = (wave & 1) * 32;

  f32x4 acc[4][2];
  #pragma unroll
  for (int i = 0; i < 4; i++)
    #pragma unroll
    for (int j = 0; j < 2; j++)
      acc[i][j] = (f32x4){0.f, 0.f, 0.f, 0.f};

  const int lrow = lane >> 2, lcol = (lane & 3) * 8;
  const ushort* Ag = A  + (size_t)(m0 + wave * 32 + lrow) * K + lcol;
  const ushort* Bg = Bw + (size_t)(n0 + wave * 16 + lrow) * K + lcol;  // 16 rows/wave; lrow<16 half
  const int ldsoA = (wave * 32) * 32;
  const int ldsoB = (wave * 16) * 32;
  // B staging uses 16 rows per wave: lanes 0..63 cover rows lane>>2 in [0,16)
  for (int k0 = 0; k0 < K; k0 += 64) {
    __syncthreads();
    #pragma unroll
    for (int c = 0; c < 2; c++) {
      async_cp16(Ag + k0 + c * 32,                  &As[c][ldsoA]);
      async_cp16(Ag + (size_t)16 * K + k0 + c * 32, &As[c][ldsoA + 16 * 32]);
      async_cp16(Bg + k0 + c * 32,                  &Bs[c][ldsoB]);
    }
    __syncthreads();
    #pragma unroll
    for (int c = 0; c < 2; c++) {
      short8 af[4], bf[2];
      #pragma unroll
      for (int tm = 0; tm < 4; tm++)
        af[tm] = *(const short8*)&As[c][(wrow + tm * 16 + col) * 32 + quad * 8];
      #pragma unroll
      for (int tn = 0; tn < 2; tn++)
        bf[tn] = *(const short8*)&Bs[c][(wcol + tn * 16 + col) * 32 + quad * 8];
      #pragma unroll
      for (int tm = 0; tm < 4; tm++)
        #pragma unroll
        for (int tn = 0; tn < 2; tn++)
          acc[tm][tn] = MFMA_BF16(af[tm], bf[tn], acc[tm][tn], 0, 0, 0);
    }
  }

  #pragma unroll
  for (int tm = 0; tm < 4; tm++) {
    #pragma unroll
    for (int tn = 0; tn < 2; tn++) {
      const int n = n0 + wcol + tn * 16 + col;
      const float bn = bias[n];
      #pragma unroll
      for (int r = 0; r < 4; r++) {
        const int m = m0 + wrow + tm * 16 + quad * 4 + r;
        float v = acc[tm][tn][r] + bn;
        ((float*)outp)[(size_t)m * N + n] = v + res[(size_t)m * N + n];
      }
    }
  }
}

// ---------------- flash attention v6 ----------------
// Q: [BH,S,64] bf16 PRE-SCALED by log2(e)/8. K: [BH,S,64]. Vt: [BH,64,S].
// 512 blocks = 64 heads x 8 q-tiles(256); 4 waves, each wave 64 q (4 groups).
// XCD-clustered heads. kb unrolled by 2 with independent P buffers: two full
// score->exp->LDS->PV chains in flight per wave for latency hiding.
__global__ __launch_bounds__(256) void attn_kernel(const ushort* __restrict__ Qb,
    const ushort* __restrict__ Kb, const ushort* __restrict__ Vt,
    ushort* __restrict__ ctx) {
  const int lane = threadIdx.x & 63, wave = threadIdx.x >> 6;
  const int col = lane & 15, quad = lane >> 4;
  const int bx = blockIdx.x;
  const int bh = (bx & 7) * 8 + ((bx >> 3) & 7);
  const int qt = bx >> 6;
  const int qbase = qt * 256 + wave * 64;
  const ushort* Qh = Qb + (size_t)bh * 2048 * 64;
  const ushort* Kh = Kb + (size_t)bh * 2048 * 64;
  const ushort* Vh = Vt + (size_t)bh * 64 * 2048;

  short8 qa[4][2];
  #pragma unroll
  for (int qg = 0; qg < 4; qg++) {
    const ushort* Qr = Qh + (size_t)(qbase + qg * 16 + col) * 64 + quad * 8;
    qa[qg][0] = *(const short8*)Qr;
    qa[qg][1] = *(const short8*)(Qr + 32);
  }

  f32x4 Ot[4][4];
  float l_part[4];
  #pragma unroll
  for (int qg = 0; qg < 4; qg++) {
    l_part[qg] = 0.f;
    #pragma unroll
    for (int dt = 0; dt < 4; dt++) Ot[qg][dt] = (f32x4){0.f, 0.f, 0.f, 0.f};
  }

  __shared__ ushort P_lds[4][2][4][16][40];   // [wave][half][qg][q][key]
  const ushort* Kc = Kh + (size_t)col * 64 + quad * 8;
  const ushort* Vc = Vh + (size_t)col * 2048 + quad * 8;

  for (int kb = 0; kb < 2048; kb += 64) {
    // load both halves' K/V fragments up front (independent chains)
    short8 kf[2][2][2], vf[2][4];
    #pragma unroll
    for (int hh = 0; hh < 2; hh++) {
      const int kh = kb + hh * 32;
      #pragma unroll
      for (int kt = 0; kt < 2; kt++) {
        const ushort* Kr = Kc + (size_t)(kh + kt * 16) * 64;
        kf[hh][kt][0] = *(const short8*)Kr;
        kf[hh][kt][1] = *(const short8*)(Kr + 32);
      }
      #pragma unroll
      for (int dt = 0; dt < 4; dt++)
        vf[hh][dt] = *(const short8*)(Vc + (size_t)dt * 16 * 2048 + kh);
    }
    #pragma unroll
    for (int hh = 0; hh < 2; hh++) {
      #pragma unroll
      for (int qg = 0; qg < 4; qg++) {
        f32x4 s0 = (f32x4){0.f, 0.f, 0.f, 0.f};
        f32x4 s1 = (f32x4){0.f, 0.f, 0.f, 0.f};
        s0 = MFMA_BF16(kf[hh][0][0], qa[qg][0], s0, 0, 0, 0);
        s0 = MFMA_BF16(kf[hh][0][1], qa[qg][1], s0, 0, 0, 0);
        s1 = MFMA_BF16(kf[hh][1][0], qa[qg][0], s1, 0, 0, 0);
        s1 = MFMA_BF16(kf[hh][1][1], qa[qg][1], s1, 0, 0, 0);
        float p0 = __builtin_amdgcn_exp2f(s0[0]);
        float p1 = __builtin_amdgcn_exp2f(s0[1]);
        float p2 = __builtin_amdgcn_exp2f(s0[2]);
        float p3 = __builtin_amdgcn_exp2f(s0[3]);
        float p4 = __builtin_amdgcn_exp2f(s1[0]);
        float p5 = __builtin_amdgcn_exp2f(s1[1]);
        float p6 = __builtin_amdgcn_exp2f(s1[2]);
        float p7 = __builtin_amdgcn_exp2f(s1[3]);
        l_part[qg] += (p0 + p1) + (p2 + p3) + (p4 + p5) + (p6 + p7);
        ushort(*P)[40] = P_lds[wave][hh][qg];
        *(uint*)&P[col][quad * 4]          = pack_bf16_ru(p0, p1);
        *(uint*)&P[col][quad * 4 + 2]      = pack_bf16_ru(p2, p3);
        *(uint*)&P[col][16 + quad * 4]     = pack_bf16_ru(p4, p5);
        *(uint*)&P[col][16 + quad * 4 + 2] = pack_bf16_ru(p6, p7);
      }
      #pragma unroll
      for (int qg = 0; qg < 4; qg++) {
        short8 pf = *(const short8*)&P_lds[wave][hh][qg][col][quad * 8];
        #pragma unroll
        for (int dt = 0; dt < 4; dt++)
          Ot[qg][dt] = MFMA_BF16(vf[hh][dt], pf, Ot[qg][dt], 0, 0, 0);
      }
    }
  }

  const int bb = bh >> 4, h = bh & 15;
  #pragma unroll
  for (int qg = 0; qg < 4; qg++) {
    float l = l_part[qg];
    l += __shfl_xor(l, 16);
    l += __shfl_xor(l, 32);
    float inv = __builtin_amdgcn_rcpf(l);
    const int q = qbase + qg * 16 + col;
    size_t base = ((size_t)(bb * 2048 + q)) * 1024 + h * 64;
    #pragma unroll
    for (int dt = 0; dt < 4; dt++) {
      ushort4 o;
      o.x = f2bf(Ot[qg][dt][0] * inv);
      o.y = f2bf(Ot[qg][dt][1] * inv);
      o.z = f2bf(Ot[qg][dt][2] * inv);
      o.w = f2bf(Ot[qg][dt][3] * inv);
      *(ushort4*)&ctx[base + dt * 16 + quad * 4] = o;
    }
  }
}

// ---------------- host ----------------
extern "C" void kernel_launch(void* const* d_in, const int* in_sizes, int n_in,
                              void* d_out, int out_size, void* d_ws, size_t ws_size,
                              hipStream_t stream) {
  const float* x     = (const float*)d_in[0];
  const float* Wq    = (const float*)d_in[1];
  const float* bq    = (const float*)d_in[2];
  const float* Wk    = (const float*)d_in[3];
  const float* bk    = (const float*)d_in[4];
  const float* Wv    = (const float*)d_in[5];
  const float* bv    = (const float*)d_in[6];
  const float* Wo    = (const float*)d_in[7];
  const float* bo    = (const float*)d_in[8];
  const float* W1    = (const float*)d_in[9];
  const float* b1    = (const float*)d_in[10];
  const float* W2    = (const float*)d_in[11];
  const float* b2    = (const float*)d_in[12];
  const float* ln1_g = (const float*)d_in[13];
  const float* ln1_b = (const float*)d_in[14];
  const float* ln2_g = (const float*)d_in[15];
  const float* ln2_b = (const float*)d_in[16];

  const size_t MB = 1ull << 20;
  char* ws = (char*)d_ws;
  ushort* Wqkv_b = (ushort*)(ws + 0 * MB);    // 6 MB  [3072,1024] (Q|K|V)
  ushort* Wo_b   = (ushort*)(ws + 6 * MB);    // 2 MB
  ushort* W1_b   = (ushort*)(ws + 8 * MB);    // 8 MB
  ushort* W2_b   = (ushort*)(ws + 16 * MB);   // 8 MB
  ushort* xn1    = (ushort*)(ws + 24 * MB);   // 16 MB
  ushort* Qb     = (ushort*)(ws + 40 * MB);   // 16 MB
  ushort* Kb     = (ushort*)(ws + 56 * MB);   // 16 MB
  ushort* Vt     = (ushort*)(ws + 72 * MB);   // 16 MB
  ushort* ctxb   = (ushort*)(ws + 88 * MB);   // 16 MB
  float*  x2     = (float*)(ws + 104 * MB);   // 32 MB
  ushort* xn2    = (ushort*)(ws + 136 * MB);  // 16 MB
  ushort* y1     = (ushort*)(ws + 152 * MB);  // 64 MB -> end 216 MB
  // bqkv aliases start of y1 (lifetime-disjoint: consumed before GELU GEMM writes y1)
  float*  bqkv   = (float*)(ws + 152 * MB);

  conv_all<<<12291, 256, 0, stream>>>(Wq, Wk, Wv, Wo, W1, W2, bq, bk, bv,
                                      Wqkv_b, Wo_b, W1_b, W2_b, bqkv);

  ln_kernel<<<8192, 256, 0, stream>>>(x, ln1_g, ln1_b, xn1);

  const float cs = 0.125f * 1.4426950408889634f;  // log2(e)/sqrt(64), folded into Q
  // Q|K projections (N=2048)
  gemm_kernel<EPI_QK><<<dim3(64, 16), 256, 0, stream>>>(
      xn1, Wqkv_b, bqkv, nullptr, Qb, Kb, 1024, 2048, cs);
  // V^T projection: A = Wv (rows = v-dim), B = xn (rows = tokens) -> C[vdim, token]
  gemm_kernel<EPI_VT><<<dim3(8, 64), 256, 0, stream>>>(
      Wqkv_b + (size_t)2048 * 1024, xn1, bqkv + 2048, nullptr, Vt, nullptr,
      1024, 8192, 1.0f);

  attn_kernel<<<512, 256, 0, stream>>>(Qb, Kb, Vt, ctxb);

  gemm64_kernel<EPI_WO><<<dim3(64, 16), 256, 0, stream>>>(
      ctxb, Wo_b, bo, x, x2, 1024, 1024);

  ln_kernel<<<8192, 256, 0, stream>>>(x2, ln2_g, ln2_b, xn2);

  gemm_kernel<EPI_GELU><<<dim3(64, 32), 256, 0, stream>>>(
      xn2, W1_b, b1, nullptr, y1, nullptr, 1024, 4096, 1.0f);
  gemm64_kernel<EPI_OUT><<<dim3(64, 16), 256, 0, stream>>>(
      y1, W2_b, b2, x2, d_out, 4096, 1024);
}

// Round 7
// 568.179 us; speedup vs baseline: 1.1866x; 1.1866x over previous
//
#include <hip/hip_runtime.h>
#include <hip/hip_bf16.h>
#include <math.h>

typedef __attribute__((ext_vector_type(8))) short short8;
typedef __attribute__((ext_vector_type(4))) float f32x4;

#define MFMA_BF16 __builtin_amdgcn_mfma_f32_16x16x32_bf16

__device__ __forceinline__ ushort f2bf(float f) {
  union { __hip_bfloat16 h; ushort u; } c;
  c.h = __float2bfloat16(f);
  return c.u;
}
// round-half-up bf16 pack (positive normal floats): cheap
__device__ __forceinline__ uint pack_bf16_ru(float a, float b) {
  uint ua = __builtin_bit_cast(uint, a) + 0x8000u;
  uint ub = __builtin_bit_cast(uint, b) + 0x8000u;
  return (ua >> 16) | (ub & 0xffff0000u);
}
__device__ __forceinline__ void async_cp16(const ushort* g, ushort* l) {
  __builtin_amdgcn_global_load_lds(
      (const __attribute__((address_space(1))) void*)g,
      (__attribute__((address_space(3))) void*)l, 16, 0, 0);
}

// ------------- fused weight fp32->bf16 conversion + bias concat (one launch) -------------
__global__ __launch_bounds__(256) void conv_all(
    const float* __restrict__ Wq, const float* __restrict__ Wk,
    const float* __restrict__ Wv, const float* __restrict__ Wo,
    const float* __restrict__ W1, const float* __restrict__ W2,
    const float* __restrict__ bq, const float* __restrict__ bk,
    const float* __restrict__ bv,
    ushort* __restrict__ wqkv, ushort* __restrict__ wo,
    ushort* __restrict__ w1, ushort* __restrict__ w2,
    float* __restrict__ bqkv) {
  int i = blockIdx.x * 256 + threadIdx.x;   // float4 index
  if (i < 3145728) {
    const float* src; ushort* dst; int off;
    if (i < 786432)        { // Wq|Wk|Wv -> concatenated wqkv [3072,1024]
      dst = wqkv; off = i;
      if (i < 262144)      src = Wq + (size_t)i * 4;
      else if (i < 524288) src = Wk + (size_t)(i - 262144) * 4;
      else                 src = Wv + (size_t)(i - 524288) * 4;
    } else if (i < 1048576) { dst = wo; off = i - 786432;  src = Wo + (size_t)off * 4; }
    else if (i < 2097152)   { dst = w1; off = i - 1048576; src = W1 + (size_t)off * 4; }
    else                    { dst = w2; off = i - 2097152; src = W2 + (size_t)off * 4; }
    float4 v = *(const float4*)src;
    ushort4 o;
    o.x = f2bf(v.x); o.y = f2bf(v.y); o.z = f2bf(v.z); o.w = f2bf(v.w);
    ((ushort4*)dst)[off] = o;
  } else if (i < 3146496) {  // biases: 3 x 256 float4
    int off = i - 3145728;
    const float* src;
    if (off < 256)      src = bq + (size_t)off * 4;
    else if (off < 512) src = bk + (size_t)(off - 256) * 4;
    else                src = bv + (size_t)(off - 512) * 4;
    ((float4*)bqkv)[off] = *(const float4*)src;
  }
}

// ---------------- layernorm: one block per 1024-float row -> bf16 ----------------
__global__ __launch_bounds__(256) void ln_kernel(const float* __restrict__ x,
    const float* __restrict__ g, const float* __restrict__ b,
    ushort* __restrict__ out) {
  const int row = blockIdx.x, t = threadIdx.x;
  float4 v = ((const float4*)(x + (size_t)row * 1024))[t];
  float s  = v.x + v.y + v.z + v.w;
  float ss = v.x*v.x + v.y*v.y + v.z*v.z + v.w*v.w;
  #pragma unroll
  for (int off = 32; off >= 1; off >>= 1) {
    s  += __shfl_xor(s, off);
    ss += __shfl_xor(ss, off);
  }
  __shared__ float red[8];
  int wv = t >> 6, ln = t & 63;
  if (ln == 0) { red[wv] = s; red[4 + wv] = ss; }
  __syncthreads();
  float S  = red[0] + red[1] + red[2] + red[3];
  float SS = red[4] + red[5] + red[6] + red[7];
  float mu  = S * (1.0f/1024.0f);
  float var = SS * (1.0f/1024.0f) - mu*mu;
  float rs  = rsqrtf(var + 1e-6f);
  float4 gv = ((const float4*)g)[t];
  float4 bv = ((const float4*)b)[t];
  ushort4 o;
  o.x = f2bf((v.x-mu)*rs*gv.x + bv.x);
  o.y = f2bf((v.y-mu)*rs*gv.y + bv.y);
  o.z = f2bf((v.z-mu)*rs*gv.z + bv.z);
  o.w = f2bf((v.w-mu)*rs*gv.w + bv.w);
  ((ushort4*)(out + (size_t)row*1024))[t] = o;
}

// ---------------- 128x128 tiled bf16 GEMM, BK=64: C[m,n] = sum_k A[m,k]*Bw[n,k] ----------
enum { EPI_QK = 0, EPI_VT = 1, EPI_WO = 2, EPI_GELU = 3, EPI_OUT = 4 };

template <int EPI>
__global__ __launch_bounds__(256) void gemm_kernel(const ushort* __restrict__ A,
    const ushort* __restrict__ Bw, const float* __restrict__ bias,
    const float* __restrict__ res, void* __restrict__ outp,
    void* __restrict__ outp2, int K, int N, float scale) {
  __shared__ ushort As[2][128 * 32];
  __shared__ ushort Bs[2][128 * 32];
  const int t = threadIdx.x;
  const int m0 = blockIdx.x * 128, n0 = blockIdx.y * 128;
  const int lane = t & 63, wave = t >> 6;
  const int col = lane & 15, quad = lane >> 4;
  const int wrow = (wave >> 1) * 64, wcol = (wave & 1) * 64;

  f32x4 acc[4][4];
  #pragma unroll
  for (int i = 0; i < 4; i++)
    #pragma unroll
    for (int j = 0; j < 4; j++)
      acc[i][j] = (f32x4){0.f, 0.f, 0.f, 0.f};

  const int lrow = lane >> 2, lcol = (lane & 3) * 8;
  const ushort* Ag = A  + (size_t)(m0 + wave * 32 + lrow) * K + lcol;
  const ushort* Bg = Bw + (size_t)(n0 + wave * 32 + lrow) * K + lcol;
  const int ldso = (wave * 32) * 32;

  for (int k0 = 0; k0 < K; k0 += 64) {
    __syncthreads();
    #pragma unroll
    for (int c = 0; c < 2; c++) {
      async_cp16(Ag + k0 + c * 32,                  &As[c][ldso]);
      async_cp16(Ag + (size_t)16 * K + k0 + c * 32, &As[c][ldso + 16 * 32]);
      async_cp16(Bg + k0 + c * 32,                  &Bs[c][ldso]);
      async_cp16(Bg + (size_t)16 * K + k0 + c * 32, &Bs[c][ldso + 16 * 32]);
    }
    __syncthreads();
    #pragma unroll
    for (int c = 0; c < 2; c++) {
      short8 af[4], bf[4];
      #pragma unroll
      for (int tm = 0; tm < 4; tm++)
        af[tm] = *(const short8*)&As[c][(wrow + tm * 16 + col) * 32 + quad * 8];
      #pragma unroll
      for (int tn = 0; tn < 4; tn++)
        bf[tn] = *(const short8*)&Bs[c][(wcol + tn * 16 + col) * 32 + quad * 8];
      #pragma unroll
      for (int tm = 0; tm < 4; tm++)
        #pragma unroll
        for (int tn = 0; tn < 4; tn++)
          acc[tm][tn] = MFMA_BF16(af[tm], bf[tn], acc[tm][tn], 0, 0, 0);
    }
  }

  #pragma unroll
  for (int tm = 0; tm < 4; tm++) {
    #pragma unroll
    for (int tn = 0; tn < 4; tn++) {
      const int n = n0 + wcol + tn * 16 + col;
      const float bn = (EPI == EPI_VT) ? 0.f : bias[n];
      #pragma unroll
      for (int r = 0; r < 4; r++) {
        const int m = m0 + wrow + tm * 16 + quad * 4 + r;
        float v = acc[tm][tn][r] + bn;
        if (EPI == EPI_QK) {
          // n in [0,2048): 0..1023 -> Q (scaled), else K
          int nl = n & 1023, h = nl >> 6, hd = nl & 63;
          int bb = m >> 11, s2 = m & 2047;
          if (n < 1024)
            ((ushort*)outp)[(((size_t)(bb * 16 + h) * 2048 + s2) * 64) + hd] = f2bf(v * scale);
          else
            ((ushort*)outp2)[(((size_t)(bb * 16 + h) * 2048 + s2) * 64) + hd] = f2bf(v);
        } else if (EPI == EPI_VT) {
          // A=Wv, Bw=xn: m = v-dim, n = token. bias indexed by m.
          float vv = v + bias[m];
          int h = m >> 6, hd = m & 63, bb = n >> 11, s2 = n & 2047;
          ((ushort*)outp)[((size_t)((bb * 16 + h) * 64 + hd)) * 2048 + s2] = f2bf(vv);
        } else if (EPI == EPI_GELU) {
          float u = v * 0.7978845608028654f * (1.0f + 0.044715f * v * v);
          float e = __builtin_amdgcn_exp2f(u * 2.885390081777927f);  // e^{2u}
          float th = 1.0f - 2.0f * __builtin_amdgcn_rcpf(e + 1.0f);
          ((ushort*)outp)[(size_t)m * N + n] = f2bf(0.5f * v * (1.0f + th));
        } else {  // EPI_WO / EPI_OUT
          ((float*)outp)[(size_t)m * N + n] = v + res[(size_t)m * N + n];
        }
      }
    }
  }
}

// ---------------- flash attention v7: block-cooperative LDS staging ----------------
// Q: [BH,S,64] bf16 PRE-SCALED by log2(e)/8. K: [BH,S,64]. Vt: [BH,64,S].
// 512 blocks = 64 heads x 8 q-tiles(256); 4 waves, each wave 64 q (4 groups).
// Per 64-key chunk: stage K (as 2x[key][32d]) and Vt (as 2x[d][32key]) into LDS
// via global_load_lds (m97 layout), then all waves read MFMA fragments from LDS.
__global__ __launch_bounds__(256) void attn_kernel(const ushort* __restrict__ Qb,
    const ushort* __restrict__ Kb, const ushort* __restrict__ Vt,
    ushort* __restrict__ ctx) {
  const int lane = threadIdx.x & 63, wave = threadIdx.x >> 6;
  const int col = lane & 15, quad = lane >> 4;
  const int bx = blockIdx.x;
  const int bh = (bx & 7) * 8 + ((bx >> 3) & 7);
  const int qt = bx >> 6;
  const int qbase = qt * 256 + wave * 64;
  const ushort* Qh = Qb + (size_t)bh * 2048 * 64;
  const ushort* Kh = Kb + (size_t)bh * 2048 * 64;
  const ushort* Vh = Vt + (size_t)bh * 64 * 2048;

  short8 qa[4][2];
  #pragma unroll
  for (int qg = 0; qg < 4; qg++) {
    const ushort* Qr = Qh + (size_t)(qbase + qg * 16 + col) * 64 + quad * 8;
    qa[qg][0] = *(const short8*)Qr;
    qa[qg][1] = *(const short8*)(Qr + 32);
  }

  f32x4 Ot[4][4];
  float l_part[4];
  #pragma unroll
  for (int qg = 0; qg < 4; qg++) {
    l_part[qg] = 0.f;
    #pragma unroll
    for (int dt = 0; dt < 4; dt++) Ot[qg][dt] = (f32x4){0.f, 0.f, 0.f, 0.f};
  }

  __shared__ ushort Ks[2][64 * 32];        // [d-chunk][key*32 + d%32]
  __shared__ ushort Vs[2][64 * 32];        // [key-half][d*32 + key%32]
  __shared__ ushort P_lds[4][4][16][72];   // [wave][qg][q][key 0..63 (+pad)]

  // staging addresses (m97 lane mapping: lds dest = base + lane*16B)
  const int lrow = lane >> 2, lcol = (lane & 3) * 8;
  const ushort* Kg = Kh + (size_t)(wave * 16 + lrow) * 64 + lcol;   // + kb*64 (+32 for c1)
  const ushort* Vg = Vh + (size_t)(wave * 16 + lrow) * 2048 + lcol; // + kb (+32 for c1)
  ushort* ks0 = &Ks[0][(wave * 16) * 32];
  ushort* ks1 = &Ks[1][(wave * 16) * 32];
  ushort* vs0 = &Vs[0][(wave * 16) * 32];
  ushort* vs1 = &Vs[1][(wave * 16) * 32];

  for (int kb = 0; kb < 2048; kb += 64) {
    __syncthreads();
    async_cp16(Kg + (size_t)kb * 64,      ks0);
    async_cp16(Kg + (size_t)kb * 64 + 32, ks1);
    async_cp16(Vg + kb,                   vs0);
    async_cp16(Vg + kb + 32,              vs1);
    __syncthreads();

    // fragments from LDS (shared across the 4 q-groups)
    short8 kf[4][2], vf[4][2];
    #pragma unroll
    for (int kt = 0; kt < 4; kt++)
      #pragma unroll
      for (int c = 0; c < 2; c++)
        kf[kt][c] = *(const short8*)&Ks[c][(kt * 16 + col) * 32 + quad * 8];
    #pragma unroll
    for (int dt = 0; dt < 4; dt++)
      #pragma unroll
      for (int c = 0; c < 2; c++)
        vf[dt][c] = *(const short8*)&Vs[c][(dt * 16 + col) * 32 + quad * 8];

    #pragma unroll
    for (int qg = 0; qg < 4; qg++) {
      f32x4 s[4];
      #pragma unroll
      for (int kt = 0; kt < 4; kt++) {
        s[kt] = (f32x4){0.f, 0.f, 0.f, 0.f};
        s[kt] = MFMA_BF16(kf[kt][0], qa[qg][0], s[kt], 0, 0, 0);
        s[kt] = MFMA_BF16(kf[kt][1], qa[qg][1], s[kt], 0, 0, 0);
      }
      ushort(*P)[72] = P_lds[wave][qg];
      #pragma unroll
      for (int kt = 0; kt < 4; kt++) {
        float p0 = __builtin_amdgcn_exp2f(s[kt][0]);
        float p1 = __builtin_amdgcn_exp2f(s[kt][1]);
        float p2 = __builtin_amdgcn_exp2f(s[kt][2]);
        float p3 = __builtin_amdgcn_exp2f(s[kt][3]);
        l_part[qg] += (p0 + p1) + (p2 + p3);
        uint2 pk;
        pk.x = pack_bf16_ru(p0, p1);
        pk.y = pack_bf16_ru(p2, p3);
        *(uint2*)&P[col][kt * 16 + quad * 4] = pk;
      }
    }
    #pragma unroll
    for (int qg = 0; qg < 4; qg++) {
      #pragma unroll
      for (int c = 0; c < 2; c++) {
        short8 pf = *(const short8*)&P_lds[wave][qg][col][c * 32 + quad * 8];
        #pragma unroll
        for (int dt = 0; dt < 4; dt++)
          Ot[qg][dt] = MFMA_BF16(vf[dt][c], pf, Ot[qg][dt], 0, 0, 0);
      }
    }
  }

  const int bb = bh >> 4, h = bh & 15;
  #pragma unroll
  for (int qg = 0; qg < 4; qg++) {
    float l = l_part[qg];
    l += __shfl_xor(l, 16);
    l += __shfl_xor(l, 32);
    float inv = __builtin_amdgcn_rcpf(l);
    const int q = qbase + qg * 16 + col;
    size_t base = ((size_t)(bb * 2048 + q)) * 1024 + h * 64;
    #pragma unroll
    for (int dt = 0; dt < 4; dt++) {
      ushort4 o;
      o.x = f2bf(Ot[qg][dt][0] * inv);
      o.y = f2bf(Ot[qg][dt][1] * inv);
      o.z = f2bf(Ot[qg][dt][2] * inv);
      o.w = f2bf(Ot[qg][dt][3] * inv);
      *(ushort4*)&ctx[base + dt * 16 + quad * 4] = o;
    }
  }
}

// ---------------- host ----------------
extern "C" void kernel_launch(void* const* d_in, const int* in_sizes, int n_in,
                              void* d_out, int out_size, void* d_ws, size_t ws_size,
                              hipStream_t stream) {
  const float* x     = (const float*)d_in[0];
  const float* Wq    = (const float*)d_in[1];
  const float* bq    = (const float*)d_in[2];
  const float* Wk    = (const float*)d_in[3];
  const float* bk    = (const float*)d_in[4];
  const float* Wv    = (const float*)d_in[5];
  const float* bv    = (const float*)d_in[6];
  const float* Wo    = (const float*)d_in[7];
  const float* bo    = (const float*)d_in[8];
  const float* W1    = (const float*)d_in[9];
  const float* b1    = (const float*)d_in[10];
  const float* W2    = (const float*)d_in[11];
  const float* b2    = (const float*)d_in[12];
  const float* ln1_g = (const float*)d_in[13];
  const float* ln1_b = (const float*)d_in[14];
  const float* ln2_g = (const float*)d_in[15];
  const float* ln2_b = (const float*)d_in[16];

  const size_t MB = 1ull << 20;
  char* ws = (char*)d_ws;
  ushort* Wqkv_b = (ushort*)(ws + 0 * MB);    // 6 MB  [3072,1024] (Q|K|V)
  ushort* Wo_b   = (ushort*)(ws + 6 * MB);    // 2 MB
  ushort* W1_b   = (ushort*)(ws + 8 * MB);    // 8 MB
  ushort* W2_b   = (ushort*)(ws + 16 * MB);   // 8 MB
  ushort* xn1    = (ushort*)(ws + 24 * MB);   // 16 MB
  ushort* Qb     = (ushort*)(ws + 40 * MB);   // 16 MB
  ushort* Kb     = (ushort*)(ws + 56 * MB);   // 16 MB
  ushort* Vt     = (ushort*)(ws + 72 * MB);   // 16 MB
  ushort* ctxb   = (ushort*)(ws + 88 * MB);   // 16 MB
  float*  x2     = (float*)(ws + 104 * MB);   // 32 MB
  ushort* xn2    = (ushort*)(ws + 136 * MB);  // 16 MB
  ushort* y1     = (ushort*)(ws + 152 * MB);  // 64 MB -> end 216 MB
  // bqkv aliases start of y1 (lifetime-disjoint: consumed before GELU GEMM writes y1)
  float*  bqkv   = (float*)(ws + 152 * MB);

  conv_all<<<12291, 256, 0, stream>>>(Wq, Wk, Wv, Wo, W1, W2, bq, bk, bv,
                                      Wqkv_b, Wo_b, W1_b, W2_b, bqkv);

  ln_kernel<<<8192, 256, 0, stream>>>(x, ln1_g, ln1_b, xn1);

  const float cs = 0.125f * 1.4426950408889634f;  // log2(e)/sqrt(64), folded into Q
  // Q|K projections (N=2048)
  gemm_kernel<EPI_QK><<<dim3(64, 16), 256, 0, stream>>>(
      xn1, Wqkv_b, bqkv, nullptr, Qb, Kb, 1024, 2048, cs);
  // V^T projection: A = Wv (rows = v-dim), B = xn (rows = tokens) -> C[vdim, token]
  gemm_kernel<EPI_VT><<<dim3(8, 64), 256, 0, stream>>>(
      Wqkv_b + (size_t)2048 * 1024, xn1, bqkv + 2048, nullptr, Vt, nullptr,
      1024, 8192, 1.0f);

  attn_kernel<<<512, 256, 0, stream>>>(Qb, Kb, Vt, ctxb);

  gemm_kernel<EPI_WO><<<dim3(64, 8), 256, 0, stream>>>(
      ctxb, Wo_b, bo, x, x2, nullptr, 1024, 1024, 1.0f);

  ln_kernel<<<8192, 256, 0, stream>>>(x2, ln2_g, ln2_b, xn2);

  gemm_kernel<EPI_GELU><<<dim3(64, 32), 256, 0, stream>>>(
      xn2, W1_b, b1, nullptr, y1, nullptr, 1024, 4096, 1.0f);
  gemm_kernel<EPI_OUT><<<dim3(64, 8), 256, 0, stream>>>(
      y1, W2_b, b2, x2, d_out, nullptr, 4096, 1024, 1.0f);
}